// Round 24
// baseline (161.139 us; speedup 1.0000x reference)
//
#include <hip/hip_runtime.h>
#include <hip/hip_fp16.h>

// MultiHeadAttention_64106681860559 — round 24: R23 base (best, 149.9 us) with
// the final GEMM converted from split-K=4 (+reduce kernel) to a no-split
// 128x128-tile GEMM writing f32+bias directly. reduce_bias4 and the partials
// buffer die; fp32 accumulation over full K (slightly better accuracy).
// Lean single-barrier counted-vmcnt skeleton (R23-proven invariants).
//
// Workspace (~128 MB):
//   xb fp16 [4096][1024] @0 | wqkvT fp16 [3072][1024] @8M | qkv fp16 [4096][3072] @14M
//   S fp16 [4096][4096] @46M | P fp16 [4096][4096] @78M | vwT fp16 [1024][4096] @118M
//   woutT fp16 [1024][1024] @126M

typedef _Float16 half_t;
typedef _Float16 half8 __attribute__((ext_vector_type(8)));
typedef _Float16 half4 __attribute__((ext_vector_type(4)));
typedef float f32x4 __attribute__((ext_vector_type(4)));

static constexpr int N_TOK = 4096;
static constexpr int LATENT = 1024;
static constexpr int QKVN = 3072;

#define DEVI __device__ __forceinline__
#define BAR() __builtin_amdgcn_s_barrier()
#define PRIO(x) __builtin_amdgcn_s_setprio(x)
#define VMCNT(n) asm volatile("s_waitcnt vmcnt(" #n ")" ::: "memory")

DEVI void gld_lds16(const half_t* g, half_t* l) {
  __builtin_amdgcn_global_load_lds(
      (const __attribute__((address_space(1))) void*)g,
      (__attribute__((address_space(3))) void*)l,
      16, 0, 0);
}

DEVI f32x4 MFMA(half8 a, half8 b, f32x4 c) {
  return __builtin_amdgcn_mfma_f32_16x16x32_f16(a, b, c, 0, 0, 0);
}

// ---- 64B-row swizzle (0 conflicts, proven): phys 16B slot p of row r holds
// logical slot p ^ ((r>>1)&3). Pre-swizzled source; XOR on read.

// Stage a [256][32] fp16 half-K-tile (1024 x 16B chunks, 512 thr, 2 each).
DEVI void stageH(const half_t* __restrict__ g, int ld, half_t* lbase, int tid) {
#pragma unroll
  for (int i = 0; i < 2; ++i) {
    int c = tid + i * 512;
    int r = c >> 2;
    int k8 = ((c & 3) ^ ((r >> 1) & 3)) * 8;
    gld_lds16(g + (size_t)r * ld + k8, lbase + c * 8);
  }
}

// Stage a [128][32] fp16 half-K-tile (512 x 16B chunks, 256 thr, 2 each).
DEVI void stageH128(const half_t* __restrict__ g, int ld, half_t* lbase, int tid) {
#pragma unroll
  for (int i = 0; i < 2; ++i) {
    int c = tid + i * 256;
    int r = c >> 2;
    int k8 = ((c & 3) ^ ((r >> 1) & 3)) * 8;
    gld_lds16(g + (size_t)r * ld + k8, lbase + c * 8);
  }
}

// ---------------------------------------------------------------------------
// 256x256 GEMM: 512 thr = 8 waves (2Mx4N), per-wave 128x64 (acc[8][4]).
// BK=64 as two 32-wide K-halves; 2 phases/K-tile, ONE barrier per phase:
//  {12 ds_reads | stage A+B next-tile-same-half | prio1 | 32 MFMA | prio0 |
//   vmcnt(4) | BAR}
// MODE 0: +bias, cols<1024 * 0.125, fp16 (qkv) | MODE 1: fp16 (S)
// ---------------------------------------------------------------------------
template <int MODE>
__launch_bounds__(512, 2)
__global__ void gemm8h(const half_t* __restrict__ A, int lda,
                       const half_t* __restrict__ B, int ldb,
                       void* __restrict__ Cout, int ldc,
                       const float* __restrict__ bias, int K) {
  __shared__ half_t Alds[2][2][256 * 32];
  __shared__ half_t Blds[2][2][256 * 32];

  const int tid = threadIdx.x;
  const int lane = tid & 63;
  const int wid = tid >> 6;

  const int nx = gridDim.x;
  const int nwg = nx * gridDim.y;
  const int bid = blockIdx.y * nx + blockIdx.x;
  const int cpx = nwg >> 3;
  const int swz = (bid & 7) * cpx + (bid >> 3);
  const int rowBlk = (swz / nx) * 256;
  const int colBlk = (swz % nx) * 256;

  const int wr = (wid >> 2) * 128;
  const int wc = (wid & 3) * 64;
  const int fr = lane & 15;
  const int fs = lane >> 4;

  const half_t* Ag = A + (size_t)rowBlk * lda;
  const half_t* Bg = B + (size_t)colBlk * ldb;

  f32x4 acc[8][4] = {};
  const int NT = K >> 6;

  stageH(Ag, lda, Alds[0][0], tid);
  stageH(Bg, ldb, Blds[0][0], tid);
  stageH(Ag + 32, lda, Alds[0][1], tid);
  stageH(Bg + 32, ldb, Blds[0][1], tid);
  VMCNT(4);
  BAR();

  for (int kt = 0; kt < NT; ++kt) {
    const int b = kt & 1;
    const bool st = (kt + 1 < NT);
    const half_t* AgN = Ag + (kt + 1) * 64;
    const half_t* BgN = Bg + (kt + 1) * 64;

    half8 af[8], bf[4];
#pragma unroll
    for (int kh = 0; kh < 2; ++kh) {
      const half_t* Ac = Alds[b][kh];
      const half_t* Bc = Blds[b][kh];
#pragma unroll
      for (int m = 0; m < 8; ++m) {
        int row = wr + m * 16 + fr;
        af[m] = *(const half8*)(Ac + row * 32 + ((fs ^ ((row >> 1) & 3)) * 8));
      }
#pragma unroll
      for (int n = 0; n < 4; ++n) {
        int row = wc + n * 16 + fr;
        bf[n] = *(const half8*)(Bc + row * 32 + ((fs ^ ((row >> 1) & 3)) * 8));
      }
      if (st) {
        stageH(AgN + kh * 32, lda, Alds[b ^ 1][kh], tid);
        stageH(BgN + kh * 32, ldb, Blds[b ^ 1][kh], tid);
      }
      PRIO(1);
#pragma unroll
      for (int m = 0; m < 8; ++m)
#pragma unroll
        for (int n = 0; n < 4; ++n)
          acc[m][n] = MFMA(af[m], bf[n], acc[m][n]);
      PRIO(0);
      if (st) VMCNT(4);
      else if (kh == 0) VMCNT(0);
      BAR();
    }
  }

  // Epilogue. C/D mapping: col = lane&15, row = (lane>>4)*4 + j.
#pragma unroll
  for (int m = 0; m < 8; ++m) {
#pragma unroll
    for (int n = 0; n < 4; ++n) {
#pragma unroll
      for (int j = 0; j < 4; ++j) {
        int row = rowBlk + wr + m * 16 + (lane >> 4) * 4 + j;
        int col = colBlk + wc + n * 16 + fr;
        float v = acc[m][n][j];
        if (MODE == 0) {
          v += bias[col];
          if (col < 1024) v *= 0.125f;  // fold 1/sqrt(DK) into q
          ((half_t*)Cout)[(size_t)row * ldc + col] = (half_t)v;
        } else {
          ((half_t*)Cout)[(size_t)row * ldc + col] = (half_t)v;
        }
      }
    }
  }
}

// ---------------------------------------------------------------------------
// Final GEMM, no split-K: out[4096][1024] = P[4096][4096] @ vwT^T + bias, f32.
// 128x128 tile, 256 thr = 4 waves (2Mx2N), per-wave 64x64 (acc[4][4]).
// Same lean phase skeleton: {8 ds_reads | stage 4 ops | prio1 | 16 MFMA |
// prio0 | vmcnt(4) | BAR}. LDS 64 KB -> 2 blocks/CU. Grid 32x8 = 256 blocks.
// ---------------------------------------------------------------------------
__launch_bounds__(256, 2)
__global__ void gemmF(const half_t* __restrict__ A,
                      const half_t* __restrict__ B,
                      const float* __restrict__ bias,
                      float* __restrict__ out) {
  __shared__ half_t Alds[2][2][128 * 32];
  __shared__ half_t Blds[2][2][128 * 32];

  const int tid = threadIdx.x;
  const int lane = tid & 63;
  const int wid = tid >> 6;
  constexpr int K = 4096;

  const int nx = gridDim.x;  // 8 (col tiles)
  const int nwg = nx * gridDim.y;  // 256
  const int bid = blockIdx.y * nx + blockIdx.x;
  const int cpx = nwg >> 3;
  const int swz = (bid & 7) * cpx + (bid >> 3);
  const int rowBlk = (swz / nx) * 128;
  const int colBlk = (swz % nx) * 128;

  const int wr = (wid >> 1) * 64;
  const int wc = (wid & 1) * 64;
  const int fr = lane & 15;
  const int fs = lane >> 4;

  const half_t* Ag = A + (size_t)rowBlk * N_TOK;
  const half_t* Bg = B + (size_t)colBlk * N_TOK;

  f32x4 acc[4][4] = {};
  const int NT = K >> 6;  // 64 K-tiles

  stageH128(Ag, N_TOK, Alds[0][0], tid);
  stageH128(Bg, N_TOK, Blds[0][0], tid);
  stageH128(Ag + 32, N_TOK, Alds[0][1], tid);
  stageH128(Bg + 32, N_TOK, Blds[0][1], tid);
  VMCNT(4);
  BAR();

  for (int kt = 0; kt < NT; ++kt) {
    const int b = kt & 1;
    const bool st = (kt + 1 < NT);
    const half_t* AgN = Ag + (kt + 1) * 64;
    const half_t* BgN = Bg + (kt + 1) * 64;

    half8 af[4], bf[4];
#pragma unroll
    for (int kh = 0; kh < 2; ++kh) {
      const half_t* Ac = Alds[b][kh];
      const half_t* Bc = Blds[b][kh];
#pragma unroll
      for (int m = 0; m < 4; ++m) {
        int row = wr + m * 16 + fr;
        af[m] = *(const half8*)(Ac + row * 32 + ((fs ^ ((row >> 1) & 3)) * 8));
      }
#pragma unroll
      for (int n = 0; n < 4; ++n) {
        int row = wc + n * 16 + fr;
        bf[n] = *(const half8*)(Bc + row * 32 + ((fs ^ ((row >> 1) & 3)) * 8));
      }
      if (st) {
        stageH128(AgN + kh * 32, N_TOK, Alds[b ^ 1][kh], tid);
        stageH128(BgN + kh * 32, N_TOK, Blds[b ^ 1][kh], tid);
      }
      PRIO(1);
#pragma unroll
      for (int m = 0; m < 4; ++m)
#pragma unroll
        for (int n = 0; n < 4; ++n)
          acc[m][n] = MFMA(af[m], bf[n], acc[m][n]);
      PRIO(0);
      if (st) VMCNT(4);
      else if (kh == 0) VMCNT(0);
      BAR();
    }
  }

  // Epilogue: f32 + bias direct.
#pragma unroll
  for (int m = 0; m < 4; ++m) {
#pragma unroll
    for (int n = 0; n < 4; ++n) {
#pragma unroll
      for (int j = 0; j < 4; ++j) {
        int row = rowBlk + wr + m * 16 + (lane >> 4) * 4 + j;
        int col = colBlk + wc + n * 16 + fr;
        out[(size_t)row * LATENT + col] = acc[m][n][j] + bias[col];
      }
    }
  }
}

// ---------------------------------------------------------------------------
// Dual-role launch: blocks 0-255 = 128x128 vwT GEMM; blocks 256-4351 = one
// softmax row each (unchanged from R19/R23).
// ---------------------------------------------------------------------------
DEVI void stage32p(const half_t* __restrict__ g, int ld, half_t* lbase, int tid) {
#pragma unroll
  for (int c = tid; c < 128 * 4; c += 256) {
    int r = c >> 2;
    int k8 = ((c & 3) ^ ((r >> 1) & 3)) * 8;
    gld_lds16(g + (size_t)r * ld + k8, lbase + c * 8);
  }
}

__launch_bounds__(256, 2)
__global__ void vwt_softmax(const half_t* __restrict__ wo,
                            const half_t* __restrict__ v,
                            half_t* __restrict__ vwT,
                            const half_t* __restrict__ S,
                            half_t* __restrict__ P) {
  __shared__ __align__(16) char smem[32768];
  const int bid = blockIdx.x;
  const int tid = threadIdx.x;

  if (bid < 256) {
    constexpr int BM = 128, BN = 128, MF = 4, NF = 4;
    half_t* At = (half_t*)smem;
    half_t* Bt = At + 2 * BM * 32;

    const int lane = tid & 63;
    const int wid = tid >> 6;
    const int swz = (bid & 7) * 32 + (bid >> 3);
    const int rowBlk = (swz >> 5) * BM;
    const int colBlk = (swz & 31) * BN;

    const int wr = (wid >> 1) * (BM / 2);
    const int wc = (wid & 1) * (BN / 2);
    const int fr = lane & 15;
    const int fs = lane >> 4;

    const half_t* Ag = wo + (size_t)rowBlk * LATENT;
    const half_t* Bg = v + (size_t)colBlk * QKVN;

    f32x4 acc[MF][NF] = {};
    const int NT = LATENT >> 5;
    stage32p(Ag, LATENT, At, tid);
    stage32p(Bg, QKVN, Bt, tid);
    __syncthreads();

    int cur = 0;
    for (int t = 0; t < NT; ++t) {
      if (t + 1 < NT) {
        stage32p(Ag + (t + 1) * 32, LATENT, At + (cur ^ 1) * BM * 32, tid);
        stage32p(Bg + (t + 1) * 32, QKVN, Bt + (cur ^ 1) * BN * 32, tid);
      }
      const half_t* Ac = At + cur * BM * 32;
      const half_t* Bc = Bt + cur * BN * 32;
      half8 af[MF], bf[NF];
#pragma unroll
      for (int m = 0; m < MF; ++m) {
        int row = wr + m * 16 + fr;
        af[m] = *(const half8*)(Ac + row * 32 + ((fs ^ ((row >> 1) & 3)) * 8));
      }
#pragma unroll
      for (int n = 0; n < NF; ++n) {
        int row = wc + n * 16 + fr;
        bf[n] = *(const half8*)(Bc + row * 32 + ((fs ^ ((row >> 1) & 3)) * 8));
      }
#pragma unroll
      for (int m = 0; m < MF; ++m)
#pragma unroll
        for (int n = 0; n < NF; ++n)
          acc[m][n] = MFMA(af[m], bf[n], acc[m][n]);
      __syncthreads();
      cur ^= 1;
    }

#pragma unroll
    for (int m = 0; m < MF; ++m)
#pragma unroll
      for (int n = 0; n < NF; ++n)
#pragma unroll
        for (int j = 0; j < 4; ++j) {
          int row = rowBlk + wr + m * 16 + (lane >> 4) * 4 + j;
          int col = colBlk + wc + n * 16 + fr;
          vwT[(size_t)row * N_TOK + col] = (half_t)acc[m][n][j];
        }
  } else {
    const int row = bid - 256;
    float* redm = (float*)smem;
    float* reds = redm + 4;
    const half8* s8 = (const half8*)(S + (size_t)row * N_TOK);

    half8 vv[2];
    float lmax = -1e30f;
#pragma unroll
    for (int i = 0; i < 2; ++i) {
      vv[i] = s8[tid + i * 256];
#pragma unroll
      for (int j = 0; j < 8; ++j) lmax = fmaxf(lmax, (float)vv[i][j]);
    }
#pragma unroll
    for (int off = 32; off; off >>= 1) lmax = fmaxf(lmax, __shfl_xor(lmax, off));
    if ((tid & 63) == 0) redm[tid >> 6] = lmax;
    __syncthreads();
    lmax = fmaxf(fmaxf(redm[0], redm[1]), fmaxf(redm[2], redm[3]));

    float e[16];
    float lsum = 0.f;
#pragma unroll
    for (int i = 0; i < 2; ++i)
#pragma unroll
      for (int j = 0; j < 8; ++j) {
        float ev = __expf((float)vv[i][j] - lmax);
        e[i * 8 + j] = ev;
        lsum += ev;
      }
#pragma unroll
    for (int off = 32; off; off >>= 1) lsum += __shfl_xor(lsum, off);
    if ((tid & 63) == 0) reds[tid >> 6] = lsum;
    __syncthreads();
    float inv = 1.f / (reds[0] + reds[1] + reds[2] + reds[3]);

    half8* p8 = (half8*)(P + (size_t)row * N_TOK);
#pragma unroll
    for (int i = 0; i < 2; ++i) {
      half8 h;
#pragma unroll
      for (int j = 0; j < 8; ++j) h[j] = (half_t)(e[i * 8 + j] * inv);
      p8[tid + i * 256] = h;
    }
  }
}

// ---------------------------------------------------------------------------
// Preamble (single launch, 8192 blocks): [0,4096) cvt x->fp16 (1M float4s);
// [4096,7168) transpose w_qkv; [7168,8192) transpose w_out.
// ---------------------------------------------------------------------------
DEVI void tr32(const float* __restrict__ in, int ldin,
               half_t* __restrict__ out, int ldout,
               int cb, int rb, int tid, float (*tile)[33]) {
  const int tx = tid & 31;
  const int ty = tid >> 5;
#pragma unroll
  for (int i = ty; i < 32; i += 8)
    tile[i][tx] = in[(size_t)(rb + i) * ldin + cb + tx];
  __syncthreads();
#pragma unroll
  for (int i = ty; i < 32; i += 8)
    out[(size_t)(cb + i) * ldout + rb + tx] = (half_t)tile[tx][i];
}

__launch_bounds__(256)
__global__ void preamble(const float* __restrict__ x, half_t* __restrict__ xb,
                         const float* __restrict__ wq, half_t* __restrict__ wqT,
                         const float* __restrict__ wo, half_t* __restrict__ woT) {
  __shared__ float tile[32][33];
  const int bid = blockIdx.x;
  const int tid = threadIdx.x;
  if (bid < 4096) {
    int i = bid * 256 + tid;  // float4 index, 4096*256 = 1M = all of x
    float4 v = ((const float4*)x)[i];
    half4 h;
    h[0] = (half_t)v.x; h[1] = (half_t)v.y; h[2] = (half_t)v.z; h[3] = (half_t)v.w;
    ((half4*)xb)[i] = h;
  } else if (bid < 7168) {
    int l = bid - 4096;  // 3072 tiles: 96 cols x 32 rows
    tr32(wq, QKVN, wqT, LATENT, (l % 96) * 32, (l / 96) * 32, tid, tile);
  } else {
    int l = bid - 7168;  // 1024 tiles: 32 x 32
    tr32(wo, LATENT, woT, LATENT, (l & 31) * 32, (l >> 5) * 32, tid, tile);
  }
}

extern "C" void kernel_launch(void* const* d_in, const int* in_sizes, int n_in,
                              void* d_out, int out_size, void* d_ws, size_t ws_size,
                              hipStream_t stream) {
  const float* x = (const float*)d_in[0];
  const float* w_qkv = (const float*)d_in[1];
  const float* b_qkv = (const float*)d_in[2];
  const float* w_out = (const float*)d_in[3];
  const float* b_out = (const float*)d_in[4];
  float* out = (float*)d_out;

  char* ws = (char*)d_ws;
  half_t* xb    = (half_t*)(ws);
  half_t* wqkvT = (half_t*)(ws + ((size_t)8 << 20));
  half_t* qkv   = (half_t*)(ws + ((size_t)14 << 20));
  half_t* S     = (half_t*)(ws + ((size_t)46 << 20));
  half_t* P     = (half_t*)(ws + ((size_t)78 << 20));
  half_t* vwT   = (half_t*)(ws + ((size_t)118 << 20));
  half_t* woutT = (half_t*)(ws + ((size_t)126 << 20));

  // 1. preamble: cvt + both transposes in one launch (8192 blocks)
  preamble<<<8192, 256, 0, stream>>>(x, xb, w_qkv, wqkvT, w_out, woutT);
  // 2. qkv = x @ w_qkv + b (q scaled 0.125)  (192 blocks @ 256x256)
  gemm8h<0><<<dim3(QKVN / 256, N_TOK / 256), 512, 0, stream>>>(
      xb, LATENT, wqkvT, LATENT, qkv, QKVN, b_qkv, LATENT);
  // 3. S = q' @ k^T  (256 blocks @ 256x256)
  gemm8h<1><<<dim3(N_TOK / 256, N_TOK / 256), 512, 0, stream>>>(
      qkv, QKVN, qkv + LATENT, QKVN, S, N_TOK, nullptr, LATENT);
  // 4. dual-role: vwT GEMM (256 blocks) + softmax rows (4096 blocks)
  vwt_softmax<<<256 + N_TOK, 256, 0, stream>>>(
      woutT, qkv + 2 * LATENT, vwT, S, P);
  // 5. out = P @ vwT + b_out, f32, no split-K  (256 blocks @ 128x128)
  gemmF<<<dim3(LATENT / 128, N_TOK / 128), 256, 0, stream>>>(
      P, vwT, b_out, out);
}

// Round 25
// 149.904 us; speedup vs baseline: 1.0749x; 1.0749x over previous
//
#include <hip/hip_runtime.h>
#include <hip/hip_fp16.h>

// MultiHeadAttention_64106681860559 — round 25: FINAL = R23 exact (best
// measured, 149.9 us). R24's no-split final GEMM reverted (61 > 42+12).
// Pipeline: preamble(cvt+transposes) -> qkv GEMM -> S GEMM -> dual-role
// (vwT GEMM || softmax rows) -> final GEMM split-K=4 -> reduce+bias.
// gemm8h: 256x256 tile, 8 waves, BK=64 2-phase dbuf, counted vmcnt(4),
// ONE barrier/phase, setprio around MFMA, 0-conflict LDS swizzle, XCD remap.
//
// Workspace (~128 MB):
//   xb fp16 [4096][1024] @0 | wqkvT fp16 [3072][1024] @8M | qkv fp16 [4096][3072] @14M
//   S fp16 [4096][4096] @46M | P fp16 [4096][4096] @78M | vwT fp16 [1024][4096] @118M
//   woutT fp16 [1024][1024] @126M | parts fp16 4x[4096][1024] @14M (qkv+S dead)

typedef _Float16 half_t;
typedef _Float16 half8 __attribute__((ext_vector_type(8)));
typedef _Float16 half4 __attribute__((ext_vector_type(4)));
typedef float f32x4 __attribute__((ext_vector_type(4)));

static constexpr int N_TOK = 4096;
static constexpr int LATENT = 1024;
static constexpr int QKVN = 3072;

#define DEVI __device__ __forceinline__
#define BAR() __builtin_amdgcn_s_barrier()
#define PRIO(x) __builtin_amdgcn_s_setprio(x)
#define VMCNT(n) asm volatile("s_waitcnt vmcnt(" #n ")" ::: "memory")

DEVI void gld_lds16(const half_t* g, half_t* l) {
  __builtin_amdgcn_global_load_lds(
      (const __attribute__((address_space(1))) void*)g,
      (__attribute__((address_space(3))) void*)l,
      16, 0, 0);
}

DEVI f32x4 MFMA(half8 a, half8 b, f32x4 c) {
  return __builtin_amdgcn_mfma_f32_16x16x32_f16(a, b, c, 0, 0, 0);
}

// ---- 64B-row swizzle (0 conflicts, proven): phys 16B slot p of row r holds
// logical slot p ^ ((r>>1)&3). Pre-swizzled source; XOR on read.

// Stage a [256][32] fp16 half-K-tile (1024 x 16B chunks, 512 thr, 2 each).
DEVI void stageH(const half_t* __restrict__ g, int ld, half_t* lbase, int tid) {
#pragma unroll
  for (int i = 0; i < 2; ++i) {
    int c = tid + i * 512;
    int r = c >> 2;
    int k8 = ((c & 3) ^ ((r >> 1) & 3)) * 8;
    gld_lds16(g + (size_t)r * ld + k8, lbase + c * 8);
  }
}

// ---------------------------------------------------------------------------
// 256x256 GEMM: 512 thr = 8 waves (2Mx4N), per-wave 128x64 (acc[8][4]).
// BK=64 as two 32-wide K-halves; 2 phases/K-tile, ONE barrier per phase:
//  {12 ds_reads | stage A+B next-tile-same-half | prio1 | 32 MFMA | prio0 |
//   vmcnt(4) | BAR}
// MODE 0: +bias, cols<1024 * 0.125, fp16 (qkv) | MODE 1: fp16 (S) |
// MODE 2: fp16 z-sliced partials (split-K final)
// ---------------------------------------------------------------------------
template <int MODE>
__launch_bounds__(512, 2)
__global__ void gemm8h(const half_t* __restrict__ A, int lda,
                       const half_t* __restrict__ B, int ldb,
                       void* __restrict__ Cout, int ldc,
                       const float* __restrict__ bias, int K) {
  __shared__ half_t Alds[2][2][256 * 32];
  __shared__ half_t Blds[2][2][256 * 32];

  const int tid = threadIdx.x;
  const int lane = tid & 63;
  const int wid = tid >> 6;

  const int nx = gridDim.x;
  const int nwg = nx * gridDim.y;
  const int bid = blockIdx.y * nx + blockIdx.x;
  const int cpx = nwg >> 3;
  const int swz = (bid & 7) * cpx + (bid >> 3);
  const int rowBlk = (swz / nx) * 256;
  const int colBlk = (swz % nx) * 256;

  const int wr = (wid >> 2) * 128;
  const int wc = (wid & 3) * 64;
  const int fr = lane & 15;
  const int fs = lane >> 4;

  const int kOff = blockIdx.z * K;
  const half_t* Ag = A + (size_t)rowBlk * lda + kOff;
  const half_t* Bg = B + (size_t)colBlk * ldb + kOff;

  f32x4 acc[8][4] = {};
  const int NT = K >> 6;

  stageH(Ag, lda, Alds[0][0], tid);
  stageH(Bg, ldb, Blds[0][0], tid);
  stageH(Ag + 32, lda, Alds[0][1], tid);
  stageH(Bg + 32, ldb, Blds[0][1], tid);
  VMCNT(4);
  BAR();

  for (int kt = 0; kt < NT; ++kt) {
    const int b = kt & 1;
    const bool st = (kt + 1 < NT);
    const half_t* AgN = Ag + (kt + 1) * 64;
    const half_t* BgN = Bg + (kt + 1) * 64;

    half8 af[8], bf[4];
#pragma unroll
    for (int kh = 0; kh < 2; ++kh) {
      const half_t* Ac = Alds[b][kh];
      const half_t* Bc = Blds[b][kh];
#pragma unroll
      for (int m = 0; m < 8; ++m) {
        int row = wr + m * 16 + fr;
        af[m] = *(const half8*)(Ac + row * 32 + ((fs ^ ((row >> 1) & 3)) * 8));
      }
#pragma unroll
      for (int n = 0; n < 4; ++n) {
        int row = wc + n * 16 + fr;
        bf[n] = *(const half8*)(Bc + row * 32 + ((fs ^ ((row >> 1) & 3)) * 8));
      }
      if (st) {
        stageH(AgN + kh * 32, lda, Alds[b ^ 1][kh], tid);
        stageH(BgN + kh * 32, ldb, Blds[b ^ 1][kh], tid);
      }
      // (pre-MFMA barrier removed: RAW covered by previous phase's vmcnt+BAR;
      //  WAR covered by one-barrier-per-phase drift bound)
      PRIO(1);
#pragma unroll
      for (int m = 0; m < 8; ++m)
#pragma unroll
        for (int n = 0; n < 4; ++n)
          acc[m][n] = MFMA(af[m], bf[n], acc[m][n]);
      PRIO(0);
      if (st) VMCNT(4);
      else if (kh == 0) VMCNT(0);
      BAR();
    }
  }

  // Epilogue. C/D mapping: col = lane&15, row = (lane>>4)*4 + j.
  const size_t zoff = (MODE == 2) ? (size_t)blockIdx.z * N_TOK * ldc : 0;
#pragma unroll
  for (int m = 0; m < 8; ++m) {
#pragma unroll
    for (int n = 0; n < 4; ++n) {
#pragma unroll
      for (int j = 0; j < 4; ++j) {
        int row = rowBlk + wr + m * 16 + (lane >> 4) * 4 + j;
        int col = colBlk + wc + n * 16 + fr;
        float v = acc[m][n][j];
        if (MODE == 0) {
          v += bias[col];
          if (col < 1024) v *= 0.125f;  // fold 1/sqrt(DK) into q
          ((half_t*)Cout)[(size_t)row * ldc + col] = (half_t)v;
        } else if (MODE == 1) {
          ((half_t*)Cout)[(size_t)row * ldc + col] = (half_t)v;
        } else {
          ((half_t*)Cout)[zoff + (size_t)row * ldc + col] = (half_t)v;
        }
      }
    }
  }
}

// ---------------------------------------------------------------------------
// Dual-role launch: blocks 0-255 = 128x128 vwT GEMM; blocks 256-4351 = one
// softmax row each.
// ---------------------------------------------------------------------------
DEVI void stage32p(const half_t* __restrict__ g, int ld, half_t* lbase, int tid) {
#pragma unroll
  for (int c = tid; c < 128 * 4; c += 256) {
    int r = c >> 2;
    int k8 = ((c & 3) ^ ((r >> 1) & 3)) * 8;
    gld_lds16(g + (size_t)r * ld + k8, lbase + c * 8);
  }
}

__launch_bounds__(256, 2)
__global__ void vwt_softmax(const half_t* __restrict__ wo,
                            const half_t* __restrict__ v,
                            half_t* __restrict__ vwT,
                            const half_t* __restrict__ S,
                            half_t* __restrict__ P) {
  __shared__ __align__(16) char smem[32768];
  const int bid = blockIdx.x;
  const int tid = threadIdx.x;

  if (bid < 256) {
    constexpr int BM = 128, BN = 128, MF = 4, NF = 4;
    half_t* At = (half_t*)smem;
    half_t* Bt = At + 2 * BM * 32;

    const int lane = tid & 63;
    const int wid = tid >> 6;
    const int swz = (bid & 7) * 32 + (bid >> 3);
    const int rowBlk = (swz >> 5) * BM;
    const int colBlk = (swz & 31) * BN;

    const int wr = (wid >> 1) * (BM / 2);
    const int wc = (wid & 1) * (BN / 2);
    const int fr = lane & 15;
    const int fs = lane >> 4;

    const half_t* Ag = wo + (size_t)rowBlk * LATENT;
    const half_t* Bg = v + (size_t)colBlk * QKVN;

    f32x4 acc[MF][NF] = {};
    const int NT = LATENT >> 5;
    stage32p(Ag, LATENT, At, tid);
    stage32p(Bg, QKVN, Bt, tid);
    __syncthreads();

    int cur = 0;
    for (int t = 0; t < NT; ++t) {
      if (t + 1 < NT) {
        stage32p(Ag + (t + 1) * 32, LATENT, At + (cur ^ 1) * BM * 32, tid);
        stage32p(Bg + (t + 1) * 32, QKVN, Bt + (cur ^ 1) * BN * 32, tid);
      }
      const half_t* Ac = At + cur * BM * 32;
      const half_t* Bc = Bt + cur * BN * 32;
      half8 af[MF], bf[NF];
#pragma unroll
      for (int m = 0; m < MF; ++m) {
        int row = wr + m * 16 + fr;
        af[m] = *(const half8*)(Ac + row * 32 + ((fs ^ ((row >> 1) & 3)) * 8));
      }
#pragma unroll
      for (int n = 0; n < NF; ++n) {
        int row = wc + n * 16 + fr;
        bf[n] = *(const half8*)(Bc + row * 32 + ((fs ^ ((row >> 1) & 3)) * 8));
      }
#pragma unroll
      for (int m = 0; m < MF; ++m)
#pragma unroll
        for (int n = 0; n < NF; ++n)
          acc[m][n] = MFMA(af[m], bf[n], acc[m][n]);
      __syncthreads();
      cur ^= 1;
    }

#pragma unroll
    for (int m = 0; m < MF; ++m)
#pragma unroll
      for (int n = 0; n < NF; ++n)
#pragma unroll
        for (int j = 0; j < 4; ++j) {
          int row = rowBlk + wr + m * 16 + (lane >> 4) * 4 + j;
          int col = colBlk + wc + n * 16 + fr;
          vwT[(size_t)row * N_TOK + col] = (half_t)acc[m][n][j];
        }
  } else {
    const int row = bid - 256;
    float* redm = (float*)smem;
    float* reds = redm + 4;
    const half8* s8 = (const half8*)(S + (size_t)row * N_TOK);

    half8 vv[2];
    float lmax = -1e30f;
#pragma unroll
    for (int i = 0; i < 2; ++i) {
      vv[i] = s8[tid + i * 256];
#pragma unroll
      for (int j = 0; j < 8; ++j) lmax = fmaxf(lmax, (float)vv[i][j]);
    }
#pragma unroll
    for (int off = 32; off; off >>= 1) lmax = fmaxf(lmax, __shfl_xor(lmax, off));
    if ((tid & 63) == 0) redm[tid >> 6] = lmax;
    __syncthreads();
    lmax = fmaxf(fmaxf(redm[0], redm[1]), fmaxf(redm[2], redm[3]));

    float e[16];
    float lsum = 0.f;
#pragma unroll
    for (int i = 0; i < 2; ++i)
#pragma unroll
      for (int j = 0; j < 8; ++j) {
        float ev = __expf((float)vv[i][j] - lmax);
        e[i * 8 + j] = ev;
        lsum += ev;
      }
#pragma unroll
    for (int off = 32; off; off >>= 1) lsum += __shfl_xor(lsum, off);
    if ((tid & 63) == 0) reds[tid >> 6] = lsum;
    __syncthreads();
    float inv = 1.f / (reds[0] + reds[1] + reds[2] + reds[3]);

    half8* p8 = (half8*)(P + (size_t)row * N_TOK);
#pragma unroll
    for (int i = 0; i < 2; ++i) {
      half8 h;
#pragma unroll
      for (int j = 0; j < 8; ++j) h[j] = (half_t)(e[i * 8 + j] * inv);
      p8[tid + i * 256] = h;
    }
  }
}

// ---------------------------------------------------------------------------
// Split-K reduce: out = sum of 4 fp16 partials + bias (f32 out).
// ---------------------------------------------------------------------------
__launch_bounds__(256)
__global__ void reduce_bias4(const half_t* __restrict__ p, const float* __restrict__ bias,
                             float* __restrict__ out) {
  int i = blockIdx.x * 256 + threadIdx.x;  // half8 index
  const size_t stride8 = (size_t)N_TOK * LATENT / 8;
  half8 a = ((const half8*)p)[i];
  half8 b = ((const half8*)p)[i + stride8];
  half8 c = ((const half8*)p)[i + 2 * stride8];
  half8 d = ((const half8*)p)[i + 3 * stride8];
  float4 e0 = ((const float4*)bias)[(i & 127) * 2];
  float4 e1 = ((const float4*)bias)[(i & 127) * 2 + 1];
  float r[8];
#pragma unroll
  for (int j = 0; j < 8; ++j)
    r[j] = (float)a[j] + (float)b[j] + (float)c[j] + (float)d[j];
  float4 o0, o1;
  o0.x = r[0] + e0.x; o0.y = r[1] + e0.y; o0.z = r[2] + e0.z; o0.w = r[3] + e0.w;
  o1.x = r[4] + e1.x; o1.y = r[5] + e1.y; o1.z = r[6] + e1.z; o1.w = r[7] + e1.w;
  ((float4*)out)[i * 2] = o0;
  ((float4*)out)[i * 2 + 1] = o1;
}

// ---------------------------------------------------------------------------
// Preamble (single launch, 8192 blocks): [0,4096) cvt x->fp16 (1M float4s);
// [4096,7168) transpose w_qkv; [7168,8192) transpose w_out.
// ---------------------------------------------------------------------------
DEVI void tr32(const float* __restrict__ in, int ldin,
               half_t* __restrict__ out, int ldout,
               int cb, int rb, int tid, float (*tile)[33]) {
  const int tx = tid & 31;
  const int ty = tid >> 5;
#pragma unroll
  for (int i = ty; i < 32; i += 8)
    tile[i][tx] = in[(size_t)(rb + i) * ldin + cb + tx];
  __syncthreads();
#pragma unroll
  for (int i = ty; i < 32; i += 8)
    out[(size_t)(cb + i) * ldout + rb + tx] = (half_t)tile[tx][i];
}

__launch_bounds__(256)
__global__ void preamble(const float* __restrict__ x, half_t* __restrict__ xb,
                         const float* __restrict__ wq, half_t* __restrict__ wqT,
                         const float* __restrict__ wo, half_t* __restrict__ woT) {
  __shared__ float tile[32][33];
  const int bid = blockIdx.x;
  const int tid = threadIdx.x;
  if (bid < 4096) {
    int i = bid * 256 + tid;  // float4 index, 4096*256 = 1M = all of x
    float4 v = ((const float4*)x)[i];
    half4 h;
    h[0] = (half_t)v.x; h[1] = (half_t)v.y; h[2] = (half_t)v.z; h[3] = (half_t)v.w;
    ((half4*)xb)[i] = h;
  } else if (bid < 7168) {
    int l = bid - 4096;  // 3072 tiles: 96 cols x 32 rows
    tr32(wq, QKVN, wqT, LATENT, (l % 96) * 32, (l / 96) * 32, tid, tile);
  } else {
    int l = bid - 7168;  // 1024 tiles: 32 x 32
    tr32(wo, LATENT, woT, LATENT, (l & 31) * 32, (l >> 5) * 32, tid, tile);
  }
}

extern "C" void kernel_launch(void* const* d_in, const int* in_sizes, int n_in,
                              void* d_out, int out_size, void* d_ws, size_t ws_size,
                              hipStream_t stream) {
  const float* x = (const float*)d_in[0];
  const float* w_qkv = (const float*)d_in[1];
  const float* b_qkv = (const float*)d_in[2];
  const float* w_out = (const float*)d_in[3];
  const float* b_out = (const float*)d_in[4];
  float* out = (float*)d_out;

  char* ws = (char*)d_ws;
  half_t* xb    = (half_t*)(ws);
  half_t* wqkvT = (half_t*)(ws + ((size_t)8 << 20));
  half_t* qkv   = (half_t*)(ws + ((size_t)14 << 20));
  half_t* S     = (half_t*)(ws + ((size_t)46 << 20));
  half_t* P     = (half_t*)(ws + ((size_t)78 << 20));
  half_t* vwT   = (half_t*)(ws + ((size_t)118 << 20));
  half_t* woutT = (half_t*)(ws + ((size_t)126 << 20));
  half_t* parts = (half_t*)(ws + ((size_t)14 << 20));  // qkv+S dead by then

  // 1. preamble: cvt + both transposes in one launch (8192 blocks)
  preamble<<<8192, 256, 0, stream>>>(x, xb, w_qkv, wqkvT, w_out, woutT);
  // 2. qkv = x @ w_qkv + b (q scaled 0.125)  (192 blocks @ 256x256)
  gemm8h<0><<<dim3(QKVN / 256, N_TOK / 256), 512, 0, stream>>>(
      xb, LATENT, wqkvT, LATENT, qkv, QKVN, b_qkv, LATENT);
  // 3. S = q' @ k^T  (256 blocks @ 256x256)
  gemm8h<1><<<dim3(N_TOK / 256, N_TOK / 256), 512, 0, stream>>>(
      qkv, QKVN, qkv + LATENT, QKVN, S, N_TOK, nullptr, LATENT);
  // 4. dual-role: vwT GEMM (256 blocks) + softmax rows (4096 blocks)
  vwt_softmax<<<256 + N_TOK, 256, 0, stream>>>(
      woutT, qkv + 2 * LATENT, vwT, S, P);
  // 5. parts = P @ vwT, split-K=4, fp16 partials  (4 x 64 blocks @ 256x256)
  gemm8h<2><<<dim3(LATENT / 256, N_TOK / 256, 4), 512, 0, stream>>>(
      P, N_TOK, vwT, N_TOK, parts, LATENT, nullptr, 1024);
  // 6. out = sum(parts) + b_out
  reduce_bias4<<<(N_TOK * LATENT) / (256 * 8), 256, 0, stream>>>(parts, b_out, out);
}